// Round 5
// baseline (423.536 us; speedup 1.0000x reference)
//
#include <hip/hip_runtime.h>

typedef __attribute__((ext_vector_type(8))) short short8;
typedef __attribute__((ext_vector_type(4))) float floatx4;

#define LSTR 40   // padded LDS stride (shorts) for VGPR-staged loops
#define CST 132   // padded fp32 epilogue tile stride (floats)

__device__ __forceinline__ unsigned short f2b(float f) {
  unsigned int u = __float_as_uint(f);
  unsigned int r = (u + 0x7FFFu + ((u >> 16) & 1u)) >> 16;  // RNE
  return (unsigned short)r;
}
__device__ __forceinline__ uint4 ld8f(const float* p) {
  float4 a = *(const float4*)p;
  float4 b = *(const float4*)(p + 4);
  uint4 r;
  r.x = (unsigned int)f2b(a.x) | ((unsigned int)f2b(a.y) << 16);
  r.y = (unsigned int)f2b(a.z) | ((unsigned int)f2b(a.w) << 16);
  r.z = (unsigned int)f2b(b.x) | ((unsigned int)f2b(b.y) << 16);
  r.w = (unsigned int)f2b(b.z) | ((unsigned int)f2b(b.w) << 16);
  return r;
}

#define GLL(g, l) __builtin_amdgcn_global_load_lds( \
    (const __attribute__((address_space(1))) unsigned int*)(g), \
    (__attribute__((address_space(3))) unsigned int*)(l), 16, 0, 0)

// ---- GLL K-loop (m97 style) -- used for the weight-stationary GEMMs (QKV/MLP)
__device__ __forceinline__ void kloop(const unsigned short* __restrict__ A,
                                      const unsigned short* __restrict__ B,
                                      int K, unsigned short* ldsA, unsigned short* ldsB,
                                      floatx4 (&acc)[4][4])
{
  const int tid = threadIdx.x;
  const int w = tid >> 6, lane = tid & 63;
  const int quad = lane >> 4, l16 = lane & 15;
  const int wy = w >> 1, wx = w & 1;
  const int rs = 32 * w + (lane >> 2);
  const int ks = (lane & 3) * 8;
  const int lo0 = (w * 2) * 512 + lane * 8;
  const int lo1 = lo0 + 512;
  const unsigned short* a0 = A + (size_t)rs * K + ks;
  const unsigned short* a1 = a0 + (size_t)16 * K;
  const unsigned short* b0 = B + (size_t)rs * K + ks;
  const unsigned short* b1 = b0 + (size_t)16 * K;

  for (int k0 = 0; k0 < K; k0 += 32) {
    __syncthreads();
    GLL(a0 + k0, &ldsA[lo0]);
    GLL(a1 + k0, &ldsA[lo1]);
    GLL(b0 + k0, &ldsB[lo0]);
    GLL(b1 + k0, &ldsB[lo1]);
    __syncthreads();
    short8 af[4], bf[4];
#pragma unroll
    for (int i = 0; i < 4; i++)
      af[i] = *(const short8*)&ldsA[(wy * 64 + i * 16 + l16) * 32 + quad * 8];
#pragma unroll
    for (int j = 0; j < 4; j++)
      bf[j] = *(const short8*)&ldsB[(wx * 64 + j * 16 + l16) * 32 + quad * 8];
#pragma unroll
    for (int i = 0; i < 4; i++)
#pragma unroll
      for (int j = 0; j < 4; j++)
        acc[i][j] = __builtin_amdgcn_mfma_f32_16x16x32_bf16(af[i], bf[j], acc[i][j], 0, 0, 0);
  }
}

// ---- fused QKV: C[16384,1536] split into q/k/v, bias per segment
__global__ __launch_bounds__(256, 2) void gemm_qkv(
    const unsigned short* __restrict__ x, const unsigned short* __restrict__ WT,
    const float* __restrict__ bq, const float* __restrict__ bk, const float* __restrict__ bv,
    unsigned short* __restrict__ q, unsigned short* __restrict__ kx, unsigned short* __restrict__ v)
{
  __shared__ unsigned short ldsA[4096], ldsB[4096];
  const int m0 = blockIdx.y * 128, n0 = blockIdx.x * 128;
  floatx4 acc[4][4];
#pragma unroll
  for (int i = 0; i < 4; i++)
#pragma unroll
    for (int j = 0; j < 4; j++) acc[i][j] = (floatx4){0.f, 0.f, 0.f, 0.f};

  kloop(x + (size_t)m0 * 512, WT + (size_t)n0 * 512, 512, ldsA, ldsB, acc);

  const int seg = n0 >> 9, nloc = n0 & 511;
  unsigned short* C = seg == 0 ? q : (seg == 1 ? kx : v);
  const float* bias = seg == 0 ? bq : (seg == 1 ? bk : bv);
  const int lane = threadIdx.x & 63, w = threadIdx.x >> 6;
  const int quad = lane >> 4, l16 = lane & 15, wy = w >> 1, wx = w & 1;
  float bvv[4];
#pragma unroll
  for (int j = 0; j < 4; j++) bvv[j] = bias[nloc + wx * 64 + j * 16 + l16];
#pragma unroll
  for (int i = 0; i < 4; i++)
#pragma unroll
    for (int r = 0; r < 4; r++) {
      int m = m0 + wy * 64 + i * 16 + quad * 4 + r;
      unsigned short* crow = C + (size_t)m * 512 + nloc + wx * 64 + l16;
#pragma unroll
      for (int j = 0; j < 4; j++) crow[j * 16] = f2b(acc[i][j][r] + bvv[j]);
    }
}

// ---- generic bf16 GEMM (MLP): C = act(A @ Bt^T + bias)
template<int CF32, int ACT>
__global__ __launch_bounds__(256, 2) void gemm2(
    const unsigned short* __restrict__ A, const unsigned short* __restrict__ Bt,
    const float* __restrict__ bias, void* __restrict__ Cv, int N, int K)
{
  __shared__ unsigned short ldsA[4096], ldsB[4096];
  const int m0 = blockIdx.y * 128, n0 = blockIdx.x * 128;
  floatx4 acc[4][4];
#pragma unroll
  for (int i = 0; i < 4; i++)
#pragma unroll
    for (int j = 0; j < 4; j++) acc[i][j] = (floatx4){0.f, 0.f, 0.f, 0.f};

  kloop(A + (size_t)m0 * K, Bt + (size_t)n0 * K, K, ldsA, ldsB, acc);

  const int lane = threadIdx.x & 63, w = threadIdx.x >> 6;
  const int quad = lane >> 4, l16 = lane & 15, wy = w >> 1, wx = w & 1;
  float bvv[4];
#pragma unroll
  for (int j = 0; j < 4; j++)
    bvv[j] = bias ? bias[n0 + wx * 64 + j * 16 + l16] : 0.f;
  float*          Cf = (float*)Cv;
  unsigned short* Ch = (unsigned short*)Cv;
#pragma unroll
  for (int i = 0; i < 4; i++)
#pragma unroll
    for (int r = 0; r < 4; r++) {
      int m = m0 + wy * 64 + i * 16 + quad * 4 + r;
      size_t base = (size_t)m * N + n0 + wx * 64 + l16;
#pragma unroll
      for (int j = 0; j < 4; j++) {
        float vv = acc[i][j][r] + bvv[j];
        if (ACT == 1) vv = tanhf(vv);
        if (CF32) Cf[base + j * 16] = vv;
        else      Ch[base + j * 16] = f2b(vv);
      }
    }
}

// ---- score: E = dep ? exp(clamp((q.k)*dtab[dep])) : 0 (UNNORMALIZED fp32)
//      + per-row sum atomics into S. VGPR-staged K-loop (software-pipelines).
__global__ __launch_bounds__(256, 2) void score_kernel(
    const unsigned short* __restrict__ Q, const unsigned short* __restrict__ Km,
    const int* __restrict__ dep, const float* __restrict__ dept,
    float* __restrict__ E, float* __restrict__ S)
{
  __shared__ union {
    struct { unsigned short a[128 * LSTR]; unsigned short b[128 * LSTR]; } s;
    float c[32 * CST];
  } sm;
  __shared__ float dtab[64];
  const int tid = threadIdx.x;
  if (tid < 64) dtab[tid] = dept[tid];

  const int b = blockIdx.z;
  const unsigned short* Ab = Q + (size_t)b * (1024 * 512);
  const unsigned short* Bb = Km + (size_t)b * (1024 * 512);
  const int m0 = blockIdx.y * 128, n0 = blockIdx.x * 128;
  const int lane = tid & 63, w = tid >> 6;
  const int quad = lane >> 4, l16 = lane & 15, wy = w >> 1, wx = w & 1;
  const int r0 = tid >> 2, s0 = (tid & 3) * 8;

  floatx4 acc[4][4];
#pragma unroll
  for (int i = 0; i < 4; i++)
#pragma unroll
    for (int j = 0; j < 4; j++) acc[i][j] = (floatx4){0.f, 0.f, 0.f, 0.f};

  for (int k0 = 0; k0 < 512; k0 += 32) {
    uint4 av0 = *(const uint4*)(Ab + (size_t)(m0 + r0) * 512 + k0 + s0);
    uint4 av1 = *(const uint4*)(Ab + (size_t)(m0 + r0 + 64) * 512 + k0 + s0);
    uint4 bv0 = *(const uint4*)(Bb + (size_t)(n0 + r0) * 512 + k0 + s0);
    uint4 bv1 = *(const uint4*)(Bb + (size_t)(n0 + r0 + 64) * 512 + k0 + s0);
    __syncthreads();
    *(uint4*)&sm.s.a[r0 * LSTR + s0] = av0;
    *(uint4*)&sm.s.a[(r0 + 64) * LSTR + s0] = av1;
    *(uint4*)&sm.s.b[r0 * LSTR + s0] = bv0;
    *(uint4*)&sm.s.b[(r0 + 64) * LSTR + s0] = bv1;
    __syncthreads();
    short8 af[4], bf[4];
#pragma unroll
    for (int i = 0; i < 4; i++)
      af[i] = *(const short8*)&sm.s.a[(wy * 64 + i * 16 + l16) * LSTR + quad * 8];
#pragma unroll
    for (int j = 0; j < 4; j++)
      bf[j] = *(const short8*)&sm.s.b[(wx * 64 + j * 16 + l16) * LSTR + quad * 8];
#pragma unroll
    for (int i = 0; i < 4; i++)
#pragma unroll
      for (int j = 0; j < 4; j++)
        acc[i][j] = __builtin_amdgcn_mfma_f32_16x16x32_bf16(af[i], bf[j], acc[i][j], 0, 0, 0);
  }

  const int* depb = dep + (size_t)b * 1024 * 1024;
  float* Eb = E + (size_t)b * 1024 * 1024;
  float* Sb = S + (size_t)b * 1024;
  const int cr = tid >> 3, cb = (tid & 7) * 16;

#pragma unroll
  for (int i = 0; i < 4; i++) {
    __syncthreads();
#pragma unroll
    for (int j = 0; j < 4; j++)
#pragma unroll
      for (int r = 0; r < 4; r++)
        sm.c[(wy * 16 + quad * 4 + r) * CST + wx * 64 + j * 16 + l16] = acc[i][j][r];
    __syncthreads();
    const int m = m0 + (cr >> 4) * 64 + i * 16 + (cr & 15);
    const int* dr = depb + (size_t)m * 1024 + n0 + cb;
    float* er = Eb + (size_t)m * 1024 + n0 + cb;
    const float* crow = &sm.c[cr * CST + cb];
    float ts = 0.f;
#pragma unroll
    for (int c = 0; c < 4; c++) {
      int4 d = *(const int4*)(dr + c * 4);
      float4 s = *(const float4*)(crow + c * 4);
      float4 e;
      e.x = d.x ? __expf(fminf(fmaxf(s.x * dtab[d.x & 63], -60.f), 60.f)) : 0.f;
      e.y = d.y ? __expf(fminf(fmaxf(s.y * dtab[d.y & 63], -60.f), 60.f)) : 0.f;
      e.z = d.z ? __expf(fminf(fmaxf(s.z * dtab[d.z & 63], -60.f), 60.f)) : 0.f;
      e.w = d.w ? __expf(fminf(fmaxf(s.w * dtab[d.w & 63], -60.f), 60.f)) : 0.f;
      *(float4*)(er + c * 4) = e;
      ts += (e.x + e.y) + (e.z + e.w);
    }
#pragma unroll
    for (int d = 1; d < 8; d <<= 1) ts += __shfl_xor(ts, d);
    if ((tid & 7) == 0) atomicAdd(&Sb[m], ts);
  }
}

// ---- PV: wmp = (E_unnorm @ vT^T) * inv_rowsum, A fp32 (ld8f staging), out bf16
__global__ __launch_bounds__(256, 2) void gemm_pv(
    const float* __restrict__ E, const unsigned short* __restrict__ vT,
    const float* __restrict__ S, unsigned short* __restrict__ wmp)
{
  __shared__ unsigned short ldsA[128 * LSTR];
  __shared__ unsigned short ldsB[128 * LSTR];
  const int b = blockIdx.z;
  const float* Ab = E + (size_t)b * (1024 * 1024);
  const unsigned short* Bb = vT + (size_t)b * (512 * 1024);
  const int m0 = blockIdx.y * 128, n0 = blockIdx.x * 128;
  const int tid = threadIdx.x;
  const int lane = tid & 63, w = tid >> 6;
  const int quad = lane >> 4, l16 = lane & 15, wy = w >> 1, wx = w & 1;
  const int r0 = tid >> 2, s0 = (tid & 3) * 8;

  floatx4 acc[4][4];
#pragma unroll
  for (int i = 0; i < 4; i++)
#pragma unroll
    for (int j = 0; j < 4; j++) acc[i][j] = (floatx4){0.f, 0.f, 0.f, 0.f};

  for (int k0 = 0; k0 < 1024; k0 += 32) {
    uint4 av0 = ld8f(Ab + (size_t)(m0 + r0) * 1024 + k0 + s0);
    uint4 av1 = ld8f(Ab + (size_t)(m0 + r0 + 64) * 1024 + k0 + s0);
    uint4 bv0 = *(const uint4*)(Bb + (size_t)(n0 + r0) * 1024 + k0 + s0);
    uint4 bv1 = *(const uint4*)(Bb + (size_t)(n0 + r0 + 64) * 1024 + k0 + s0);
    __syncthreads();
    *(uint4*)&ldsA[r0 * LSTR + s0] = av0;
    *(uint4*)&ldsA[(r0 + 64) * LSTR + s0] = av1;
    *(uint4*)&ldsB[r0 * LSTR + s0] = bv0;
    *(uint4*)&ldsB[(r0 + 64) * LSTR + s0] = bv1;
    __syncthreads();
    short8 af[4], bf[4];
#pragma unroll
    for (int i = 0; i < 4; i++)
      af[i] = *(const short8*)&ldsA[(wy * 64 + i * 16 + l16) * LSTR + quad * 8];
#pragma unroll
    for (int j = 0; j < 4; j++)
      bf[j] = *(const short8*)&ldsB[(wx * 64 + j * 16 + l16) * LSTR + quad * 8];
#pragma unroll
    for (int i = 0; i < 4; i++)
#pragma unroll
      for (int j = 0; j < 4; j++)
        acc[i][j] = __builtin_amdgcn_mfma_f32_16x16x32_bf16(af[i], bf[j], acc[i][j], 0, 0, 0);
  }

  const float* Sb = S + (size_t)b * 1024;
  unsigned short* Cb = wmp + (size_t)b * (1024 * 512);
#pragma unroll
  for (int i = 0; i < 4; i++)
#pragma unroll
    for (int r = 0; r < 4; r++) {
      int m = m0 + wy * 64 + i * 16 + quad * 4 + r;
      float sv = Sb[m];
      float is = sv > 0.f ? 1.f / sv : 0.f;
      unsigned short* crow = Cb + (size_t)m * 512 + n0 + wx * 64 + l16;
#pragma unroll
      for (int j = 0; j < 4; j++) crow[j * 16] = f2b(acc[i][j][r] * is);
    }
}

// ---- normalize stored E in place: w[row] *= 1/S[row]
__global__ void scale_rows(float* __restrict__ wf, const float* __restrict__ S)
{
  size_t row = blockIdx.x;
  float sv = S[row];
  float inv = sv > 0.f ? 1.f / sv : 0.f;
  float4* p = (float4*)(wf + row * 1024);
  float4 u = p[threadIdx.x];
  u.x *= inv; u.y *= inv; u.z *= inv; u.w *= inv;
  p[threadIdx.x] = u;
}

// ---- x = bf16(embed[inputs])
__global__ void build_x(const float* __restrict__ embed, const int* __restrict__ inputs,
                        unsigned short* __restrict__ x)
{
  const int row = blockIdx.x * 4 + (threadIdx.x >> 6);
  const int lane = threadIdx.x & 63;
  const float* src = embed + (size_t)inputs[row] * 512 + lane * 8;
  *(uint4*)&x[(size_t)row * 512 + lane * 8] = ld8f(src);
}

// ---- 5 weight transposes fp32->bf16, one launch
__global__ void trans_w(const float* s0, const float* s1, const float* s2,
                        const float* s3, const float* s4, unsigned short* dst)
{
  __shared__ unsigned short tile[32][33];
  const int z = blockIdx.z;
  const float* src = z == 0 ? s0 : z == 1 ? s1 : z == 2 ? s2 : z == 3 ? s3 : s4;
  unsigned short* ob = dst + (size_t)z * 262144;
  int c0 = blockIdx.x * 32, r0 = blockIdx.y * 32;
  int tx = threadIdx.x & 31, ty = threadIdx.x >> 5;
  for (int i = ty; i < 32; i += 8)
    tile[i][tx] = f2b(src[(size_t)(r0 + i) * 512 + (c0 + tx)]);
  __syncthreads();
  for (int i = ty; i < 32; i += 8)
    ob[(size_t)(c0 + i) * 512 + (r0 + tx)] = tile[tx][i];
}

// ---- bf16 transpose v -> vT, batched
__global__ void trans_v(const unsigned short* __restrict__ in, unsigned short* __restrict__ out)
{
  __shared__ unsigned short tile[32][33];
  const unsigned short* ib = in + (size_t)blockIdx.z * (1024 * 512);
  unsigned short* ob = out + (size_t)blockIdx.z * (512 * 1024);
  int c0 = blockIdx.x * 32, r0 = blockIdx.y * 32;
  int tx = threadIdx.x & 31, ty = threadIdx.x >> 5;
  for (int i = ty; i < 32; i += 8)
    tile[i][tx] = ib[(size_t)(r0 + i) * 512 + (c0 + tx)];
  __syncthreads();
  for (int i = ty; i < 32; i += 8)
    ob[(size_t)(c0 + i) * 1024 + (r0 + tx)] = tile[tx][i];
}

extern "C" void kernel_launch(void* const* d_in, const int* in_sizes, int n_in,
                              void* d_out, int out_size, void* d_ws, size_t ws_size,
                              hipStream_t stream)
{
  const int*   inputs     = (const int*)d_in[0];
  const int*   dependency = (const int*)d_in[1];
  const float* embed      = (const float*)d_in[2];
  const float* dept       = (const float*)d_in[3];
  const float* Wq = (const float*)d_in[4];   const float* bq = (const float*)d_in[5];
  const float* Wk = (const float*)d_in[6];   const float* bk = (const float*)d_in[7];
  const float* Wv = (const float*)d_in[8];   const float* bvv = (const float*)d_in[9];
  const float* W1 = (const float*)d_in[10];  const float* b1 = (const float*)d_in[11];
  const float* W2 = (const float*)d_in[12];  const float* b2 = (const float*)d_in[13];

  float* out  = (float*)d_out;                 // wm [16,1024,512] fp32 (32 MB)
  float* wout = out + (size_t)8388608;         // weights [16,1024,1024] fp32 (64 MB)

  // ws layout (shorts): q | kx | WTc(3) | W1T | W2T | S(fp32 row sums)
  unsigned short* ws   = (unsigned short*)d_ws;
  unsigned short* q    = ws;
  unsigned short* kx   = ws + 8388608;
  unsigned short* WTc  = ws + 16777216;
  unsigned short* W1T  = ws + 17563648;
  unsigned short* W2T  = ws + 17825792;
  float*          S    = (float*)(ws + 18087936);  // 16384 floats (64 KB)
  unsigned short* h    = ws;                       // over q (dead after score)

  // output-region staging (dead before final writes):
  unsigned short* x    = (unsigned short*)wout;            // bf16 x; E overwrites
  unsigned short* v    = (unsigned short*)out;             // bf16 v (lo 16 MB)
  unsigned short* vT   = (unsigned short*)out + 8388608;   // bf16 vT (hi 16 MB)
  unsigned short* wmp  = (unsigned short*)out;             // bf16 wmp (over dead v)

  dim3 blk(256);

  hipMemsetAsync(S, 0, 16384 * sizeof(float), stream);
  trans_w<<<dim3(16, 16, 5), blk, 0, stream>>>(Wq, Wk, Wv, W1, W2, WTc);
  build_x<<<dim3(4096), blk, 0, stream>>>(embed, inputs, x);

  gemm_qkv<<<dim3(12, 128, 1), blk, 0, stream>>>(x, WTc, bq, bk, bvv, q, kx, v);

  // unnormalized exp-scores + row-sum atomics
  score_kernel<<<dim3(8, 8, 16), blk, 0, stream>>>(q, kx, dependency, dept, wout, S);

  trans_v<<<dim3(16, 32, 16), blk, 0, stream>>>(v, vT);

  // wm_pre = (E @ vT^T) * inv_rowsum   (reads UNNORMALIZED E -- before scale_rows)
  gemm_pv<<<dim3(4, 8, 16), blk, 0, stream>>>(wout, vT, S, wmp);

  // normalize stored weights in place (fp32 output #1 tail)
  scale_rows<<<dim3(16384), blk, 0, stream>>>(wout, S);

  // h = tanh(wm_pre @ W1^T + b1);  wm = h @ W2^T + b2
  gemm2<0, 1><<<dim3(4, 128, 1), blk, 0, stream>>>(wmp, W1T, b1, h, 512, 512);
  gemm2<1, 0><<<dim3(4, 128, 1), blk, 0, stream>>>(h, W2T, b2, out, 512, 512);
}